// Round 4
// baseline (9330.379 us; speedup 1.0000x reference)
//
#include <hip/hip_runtime.h>
#include <math.h>

typedef unsigned short ushort_t;
typedef short short8 __attribute__((ext_vector_type(8)));
typedef float floatx4 __attribute__((ext_vector_type(4)));
typedef float float4v __attribute__((ext_vector_type(4)));
typedef unsigned int uint4v __attribute__((ext_vector_type(4)));

__device__ __forceinline__ float b2f(ushort_t u) {
    union { unsigned int i; float f; } v; v.i = ((unsigned int)u) << 16; return v.f;
}
__device__ __forceinline__ ushort_t f2b(float f) {
    union { float f; unsigned int i; } v; v.f = f;
    unsigned int x = v.i;
    return (ushort_t)((x + 0x7fffu + ((x >> 16) & 1u)) >> 16);  // RNE
}
__device__ __forceinline__ void split8(const float* v, short8& hi, short8& lo) {
#pragma unroll
    for (int e = 0; e < 8; ++e) {
        ushort_t h = f2b(v[e]);
        hi[e] = (short)h;
        lo[e] = (short)f2b(v[e] - b2f(h));
    }
}
__device__ __forceinline__ void load8f(const float* p, float* v) {
    *(float4v*)(v)     = *(const float4v*)(p);
    *(float4v*)(v + 4) = *(const float4v*)(p + 4);
}
__device__ __forceinline__ floatx4 mfma16(short8 a, short8 b, floatx4 c) {
    return __builtin_amdgcn_mfma_f32_16x16x32_bf16(a, b, c, 0, 0, 0);
}
// Coherent (LLC) 8B store: bypass L1/L2 so remote XCDs can read it.
__device__ __forceinline__ void store8_cc(void* p, unsigned long long v) {
    asm volatile("global_store_dwordx2 %0, %1, off sc0 sc1"
                 :: "v"(p), "v"(v) : "memory");
}
__device__ __forceinline__ void store4_cc(void* p, unsigned int v) {
    asm volatile("global_store_dword %0, %1, off sc0 sc1"
                 :: "v"(p), "v"(v) : "memory");
}

// Classify input encoding (fallback when in_sizes doesn't resolve it).
__global__ void detect_dtype(const unsigned int* __restrict__ x, int* __restrict__ flag) {
    __shared__ int cnt;
    if (threadIdx.x == 0) cnt = 0;
    __syncthreads();
    int c = 0;
#pragma unroll
    for (int i = 0; i < 8; ++i) {
        unsigned int w = x[threadIdx.x * 8 + i];
        unsigned int e = (w >> 7) & 0xFFu;
        if (e >= 100u && e <= 140u) ++c;
    }
    atomicAdd(&cnt, c);
    __syncthreads();
    if (threadIdx.x == 0) *flag = (cnt > 1024) ? 1 : 0;   // 1 = bf16, 0 = f32
}

// One-time pre-split of masked X into XS (d_out scratch).
__global__ __launch_bounds__(256) void prep(
    const int* __restrict__ flag,
    const void* __restrict__ x, const void* __restrict__ mask_x,
    char* __restrict__ xs)
{
    const bool isbf = (*flag != 0);
    const int i = blockIdx.x * 256 + threadIdx.x;       // 1048576 total
    const int b = i >> 15;
    const int rem = i & 32767;
    const int t = rem >> 6;
    const int c = rem & 63;
    const size_t xoff = ((size_t)(b * 512 + t)) * 512 + c * 8;
    if (isbf) {
        const ushort_t* X = (const ushort_t*)x;
        const ushort_t* M = (const ushort_t*)mask_x + b * 512 + c * 8;
        short8 o;
#pragma unroll
        for (int e = 0; e < 8; ++e) o[e] = (short)f2b(b2f(X[xoff + e]) * b2f(M[e]));
        *(short8*)(xs + ((size_t)t * 32 + b) * 1024 + c * 16) = o;
    } else {
        float v[8], m[8];
        load8f((const float*)x + xoff, v);
        load8f((const float*)mask_x + b * 512 + c * 8, m);
#pragma unroll
        for (int e = 0; e < 8; ++e) v[e] *= m[e];
        short8 hi, lo; split8(v, hi, lo);
        char* p = xs + ((size_t)t * 32 + b) * 2048 + c * 32;
        *(short8*)p = hi; *(short8*)(p + 16) = lo;
    }
}

// LDS swizzle: spreads rows and 64B-segments across banks. Pure fn of (row,o).
__device__ __forceinline__ int lds_swz(int row, int o) {
    return o ^ ((row & 7) << 4) ^ (((o >> 6) & 7) << 4);
}

// Persistent LSTM layer. 128 blocks x 512 thr. Block = (dir, j-tile, m-half);
// wave = (gate q, K-half kh). All weights register/AGPR-resident.
// Per step: x-part(s+1) pipelined behind epilogue(s); per-block flag words
// (no central atomic); wave 7 = epilogue wave; 2 block barriers per step.
template <int LAYER>
__global__ __launch_bounds__(512, 2) void lstm_phase(
    const int* __restrict__ flag,
    const char* __restrict__ xs,     // L0: XS (d_out scratch); L1: OS (ws)
    char* __restrict__ os,           // L0 writes OS here
    char* __restrict__ hs,           // h bufs: [par][dir]*64KB: hi[32][512]2B, lo +32768
    char* __restrict__ flags,        // 128 flag words, 64B apart: [(dir*2+m)*32+jt]
    const void* __restrict__ w_ih, const void* __restrict__ w_hh,
    const void* __restrict__ bias, const void* __restrict__ mask_h,
    const void* __restrict__ mask_out, void* __restrict__ dout,
    int os4_host, int write_hn)
{
    __shared__ __align__(16) char smem[40960];   // h tile 32KB + gbuf 8KB
    float* gb = (float*)(smem + 32768);
    const int dir  = blockIdx.x >> 6;
    const int b6   = blockIdx.x & 63;
    const int jt   = b6 & 31;
    const int m    = b6 >> 5;
    const int j0   = jt << 4;
    const int tid  = threadIdx.x;
    const int w    = tid >> 6;
    const int q    = w & 3;          // gate
    const int kh   = w >> 2;         // K-half
    const int lane = tid & 63;
    const int n16  = lane & 15;
    const int quad = lane >> 4;
    const bool isbf = (*flag != 0);
    const bool os4  = (!isbf) && (os4_host != 0);
    constexpr int KI = (LAYER == 0) ? 512 : 1024;   // ih K total
    constexpr int NI = KI / 128;                    // ih tiles per half... (K/2)/64
    constexpr int NIT = (KI / 2) / 32;              // ih 32-K tiles per half: 8 / 16
    constexpr int NH = 8;                           // hh 32-K tiles per half
    const int gq = q * 512 + j0 + n16;              // gate row
    (void)NI;

    // ---- one-time: weights -> registers (hi/lo) ----
    short8 wih_h[NIT], wih_l[NIT], whh_h[NH], whh_l[NH];
    if (isbf) {
        const ushort_t* WI = (const ushort_t*)w_ih + ((size_t)(dir * 2048 + gq)) * KI + kh * (KI / 2) + quad * 8;
        const ushort_t* WH = (const ushort_t*)w_hh + ((size_t)(dir * 2048 + gq)) * 512 + kh * 256 + quad * 8;
#pragma unroll
        for (int ki = 0; ki < NIT; ++ki) { wih_h[ki] = *(const short8*)(WI + ki * 32); wih_l[ki] = short8{0,0,0,0,0,0,0,0}; }
#pragma unroll
        for (int ki = 0; ki < NH; ++ki) { whh_h[ki] = *(const short8*)(WH + ki * 32); whh_l[ki] = short8{0,0,0,0,0,0,0,0}; }
    } else {
        const float* WI = (const float*)w_ih + ((size_t)(dir * 2048 + gq)) * KI + kh * (KI / 2) + quad * 8;
        const float* WH = (const float*)w_hh + ((size_t)(dir * 2048 + gq)) * 512 + kh * 256 + quad * 8;
#pragma unroll
        for (int ki = 0; ki < NIT; ++ki) { float w8[8]; load8f(WI + ki * 32, w8); split8(w8, wih_h[ki], wih_l[ki]); }
#pragma unroll
        for (int ki = 0; ki < NH; ++ki) { float w8[8]; load8f(WH + ki * 32, w8); split8(w8, whh_h[ki], whh_l[ki]); }
    }

    // x-part of gates for timestep ts (no h dependence)
    auto xpart = [&](int ts) -> floatx4 {
        floatx4 a = {0.f, 0.f, 0.f, 0.f};
        if (isbf) {
            const int stride = (LAYER == 0) ? 1024 : 2048;
            const char* xb = xs + ((size_t)ts * 32 + m * 16 + n16) * stride + (kh * NIT * 4 + quad) * 16;
#pragma unroll
            for (int ki = 0; ki < NIT; ++ki)
                a = mfma16(*(const short8*)(xb + ki * 64), wih_h[ki], a);
        } else if (LAYER == 1 && !os4) {   // compact OS: a_lo==0 exactly
            const char* xb = xs + ((size_t)ts * 32 + m * 16 + n16) * 2048 + (kh * 64 + quad) * 16;
#pragma unroll
            for (int ki = 0; ki < NIT; ++ki) {
                short8 av = *(const short8*)(xb + ki * 64);
                a = mfma16(av, wih_h[ki], a);
                a = mfma16(av, wih_l[ki], a);
            }
        } else {
            const int stride = (LAYER == 0) ? 2048 : 4096;
            const char* xb = xs + ((size_t)ts * 32 + m * 16 + n16) * stride + (kh * NIT * 4 + quad) * 32;
#pragma unroll
            for (int ki = 0; ki < NIT; ++ki) {
                short8 ah = *(const short8*)(xb + ki * 128);
                short8 al = *(const short8*)(xb + ki * 128 + 16);
                a = mfma16(ah, wih_h[ki], a);
                a = mfma16(al, wih_h[ki], a);
                a = mfma16(ah, wih_l[ki], a);
            }
        }
        return a;
    };

    // epilogue constants base pointers (loaded fresh per step; L1/L2-hot)
    const int el4 = (lane & 3) * 4;          // first of 4 consecutive j
    const int erow = m * 16 + (lane >> 2);   // batch row (wave-7 mapping)
    const int ej0 = j0 + el4;
    float creg[4] = {0.f, 0.f, 0.f, 0.f};

    const char* myflags = flags + (size_t)((dir * 2 + m) * 32) * 64;
    floatx4 acc = xpart(dir ? 511 : 0);

    for (int s = 0; s < 512; ++s) {
        const int t = dir ? (511 - s) : s;

        // ============ per-wave poll: all 32 producer flags >= s =============
        {
            const char* fb = myflags + (size_t)(lane & 31) * 64;
            int fv;
            for (;;) {
                asm volatile("global_load_dword %0, %1, off sc0 sc1\n\ts_waitcnt vmcnt(0)"
                             : "=v"(fv) : "v"(fb) : "memory");
                if (__all(fv >= s)) break;
            }
        }
        __builtin_amdgcn_sched_barrier(0);

        // ============ stage h rows [m*16, m*16+16) LLC -> LDS ==============
        {
            const char* hr = hs + (size_t)((s & 1) * 2 + dir) * 65536;
            const int planes = isbf ? 1 : 2;
            if (tid < planes * 256) {
                const int p = tid >> 8, v = tid & 255;
                const int row = v >> 4, seg = v & 15;
                const char* gsrc = hr + p * 32768 + (size_t)(m * 16 + row) * 1024 + seg * 64;
                uint4v t0, t1, t2, t3;
                asm volatile("global_load_dwordx4 %0, %1, off sc0 sc1" : "=v"(t0) : "v"(gsrc));
                asm volatile("global_load_dwordx4 %0, %1, off sc0 sc1" : "=v"(t1) : "v"(gsrc + 16));
                asm volatile("global_load_dwordx4 %0, %1, off sc0 sc1" : "=v"(t2) : "v"(gsrc + 32));
                asm volatile("global_load_dwordx4 %0, %1, off sc0 sc1" : "=v"(t3) : "v"(gsrc + 48));
                asm volatile("s_waitcnt vmcnt(0)" ::: "memory");
                __builtin_amdgcn_sched_barrier(0);
                char* lbase = smem + p * 16384 + row * 1024;
                *(uint4v*)(lbase + lds_swz(row, seg * 64))      = t0;
                *(uint4v*)(lbase + lds_swz(row, seg * 64 + 16)) = t1;
                *(uint4v*)(lbase + lds_swz(row, seg * 64 + 32)) = t2;
                *(uint4v*)(lbase + lds_swz(row, seg * 64 + 48)) = t3;
            }
        }
        __syncthreads();                                   // barrier 1

        // ============ h-part (register W_hh, LDS A-frags) ==================
        {
            const char* hrow = smem + n16 * 1024;
            if (isbf) {
#pragma unroll
                for (int ki = 0; ki < NH; ++ki) {
                    const int o = kh * 512 + ki * 64 + quad * 16;
                    acc = mfma16(*(const short8*)(hrow + lds_swz(n16, o)), whh_h[ki], acc);
                }
            } else {
#pragma unroll
                for (int ki = 0; ki < NH; ++ki) {
                    const int o = kh * 512 + ki * 64 + quad * 16;
                    const int so = lds_swz(n16, o);
                    short8 ah = *(const short8*)(hrow + so);
                    short8 al = *(const short8*)(hrow + 16384 + so);
                    acc = mfma16(ah, whh_h[ki], acc);
                    acc = mfma16(al, whh_h[ki], acc);
                    acc = mfma16(ah, whh_l[ki], acc);
                }
            }
        }

        // ============ K-half gate exchange =================================
#pragma unroll
        for (int r = 0; r < 4; ++r)
            gb[((q * 2 + kh) * 16 + quad * 4 + r) * 16 + n16] = acc[r];
        __syncthreads();                                   // barrier 2

        // ============ epilogue: wave 7 only (4 cells/lane) =================
        if (w == 7) {
            float4v gA[8];
#pragma unroll
            for (int z = 0; z < 8; ++z)
                gA[z] = *(const float4v*)(gb + z * 256 + lane * 4);

            float bi4[4], bf4[4], bg4[4], bo4[4], mh4[4], mo4[4];
            if (isbf) {
                const ushort_t* BI = (const ushort_t*)bias;
                const ushort_t* MH = (const ushort_t*)mask_h + LAYER * 16384;
#pragma unroll
                for (int u = 0; u < 4; ++u) {
                    const int ej = ej0 + u;
                    bi4[u] = b2f(BI[dir * 2048 + ej]);        bf4[u] = b2f(BI[dir * 2048 + 512 + ej]);
                    bg4[u] = b2f(BI[dir * 2048 + 1024 + ej]); bo4[u] = b2f(BI[dir * 2048 + 1536 + ej]);
                    mh4[u] = b2f(MH[erow * 512 + ej]);
                    mo4[u] = (LAYER == 0) ? b2f(((const ushort_t*)mask_out)[erow * 1024 + dir * 512 + ej]) : 0.f;
                }
            } else {
                const float* BI = (const float*)bias;
                const float* MH = (const float*)mask_h + LAYER * 16384;
                *(float4v*)bi4 = *(const float4v*)(BI + dir * 2048 + ej0);
                *(float4v*)bf4 = *(const float4v*)(BI + dir * 2048 + 512 + ej0);
                *(float4v*)bg4 = *(const float4v*)(BI + dir * 2048 + 1024 + ej0);
                *(float4v*)bo4 = *(const float4v*)(BI + dir * 2048 + 1536 + ej0);
                *(float4v*)mh4 = *(const float4v*)(MH + erow * 512 + ej0);
                if (LAYER == 0) *(float4v*)mo4 = *(const float4v*)((const float*)mask_out + erow * 1024 + dir * 512 + ej0);
            }

            float hv4[4], cn4[4];
            unsigned long long hiw = 0ull, low = 0ull;
#pragma unroll
            for (int u = 0; u < 4; ++u) {
                float ig = gA[0][u] + gA[1][u] + bi4[u];
                float fg = gA[2][u] + gA[3][u] + bf4[u];
                float gg = gA[4][u] + gA[5][u] + bg4[u];
                float og = gA[6][u] + gA[7][u] + bo4[u];
                float si = 1.f / (1.f + expf(-ig));
                float sf = 1.f / (1.f + expf(-fg));
                float so = 1.f / (1.f + expf(-og));
                float cn = sf * creg[u] + si * tanhf(gg);
                float h  = so * tanhf(cn);
                creg[u] = cn; hv4[u] = h; cn4[u] = cn;
                float hm = h * mh4[u];
                ushort_t hhi = f2b(hm);
                hiw |= (unsigned long long)hhi << (16 * u);
                low |= (unsigned long long)f2b(hm - b2f(hhi)) << (16 * u);
            }
            char* hw = hs + (size_t)(((s + 1) & 1) * 2 + dir) * 65536 + (size_t)erow * 1024 + ej0 * 2;
            store8_cc(hw, hiw);
            if (!isbf) store8_cc(hw + 32768, low);

            const int jg0 = dir * 512 + ej0;
            if constexpr (LAYER == 0) {
                unsigned long long ohi = 0ull, olo = 0ull;
#pragma unroll
                for (int u = 0; u < 4; ++u) {
                    float ho = hv4[u] * mo4[u];
                    ushort_t oh = f2b(ho);
                    ohi |= (unsigned long long)oh << (16 * u);
                    olo |= (unsigned long long)f2b(ho - b2f(oh)) << (16 * u);
                }
                if (os4) {
                    char* op = os + ((size_t)t * 32 + erow) * 4096 + (jg0 >> 3) * 32 + (jg0 & 7) * 2;
                    *(unsigned long long*)op = ohi;
                    *(unsigned long long*)(op + 16) = olo;
                } else {
                    *(unsigned long long*)(os + ((size_t)t * 32 + erow) * 2048 + (size_t)jg0 * 2) = ohi;
                }
            } else {
                size_t o1 = ((size_t)erow * 512 + t) * 1024 + jg0;
                if (isbf) {
                    unsigned long long ow = 0ull;
#pragma unroll
                    for (int u = 0; u < 4; ++u) ow |= (unsigned long long)f2b(hv4[u]) << (16 * u);
                    *(unsigned long long*)((ushort_t*)dout + o1) = ow;
                } else {
                    *(float4v*)((float*)dout + o1) = float4v{hv4[0], hv4[1], hv4[2], hv4[3]};
                }
            }
            if (s == 511 && write_hn) {
                size_t hnidx = 16777216u + (size_t)((LAYER * 2 + dir) * 32 + erow) * 512 + ej0;
                if (isbf) {
                    unsigned long long hw_ = 0ull, cw_ = 0ull;
#pragma unroll
                    for (int u = 0; u < 4; ++u) {
                        hw_ |= (unsigned long long)f2b(hv4[u]) << (16 * u);
                        cw_ |= (unsigned long long)f2b(cn4[u]) << (16 * u);
                    }
                    *(unsigned long long*)((ushort_t*)dout + hnidx) = hw_;
                    *(unsigned long long*)((ushort_t*)dout + hnidx + 65536) = cw_;
                } else {
                    *(float4v*)((float*)dout + hnidx) = float4v{hv4[0], hv4[1], hv4[2], hv4[3]};
                    *(float4v*)((float*)dout + hnidx + 65536) = float4v{cn4[0], cn4[1], cn4[2], cn4[3]};
                }
            }
            // drain this wave's stores, then post this block's flag = s+1
            asm volatile("s_waitcnt vmcnt(0)" ::: "memory");
            if (lane == 0)
                store4_cc((void*)(myflags + (size_t)jt * 64), (unsigned int)(s + 1));
        }

        // ============ pipelined x-part for step s+1 ========================
        if (s != 511) acc = xpart(dir ? (510 - s) : (s + 1));
    }
}

extern "C" void kernel_launch(void* const* d_in, const int* in_sizes, int n_in,
                              void* d_out, int out_size, void* d_ws, size_t ws_size,
                              hipStream_t stream) {
    char* ws = (char*)d_ws;
    const size_t HSB = 262144;   // h buffers: [2 par][2 dir] * 64KB
    const size_t FLB = 8192;     // 128 flag words, 64B apart
    // ws layout: [OS (67.1MB full | 33.5MB compact)][HS][flags][dtype flag]
    int os4 = (ws_size >= 67108864ull + HSB + FLB + 64) ? 1 : 0;
    size_t osb = os4 ? 67108864ull : 33554432ull;
    char* hs = ws + osb;
    char* flags = hs + HSB;
    int* flag = (int*)(flags + FLB);
    int write_hn = (out_size >= 16908288) ? 1 : 0;

    // dtype from input byte size when unambiguous; sniff otherwise.
    int hb = -1;
    if (in_sizes && n_in > 0) {
        if (in_sizes[0] == 33554432) hb = 0;        // f32 x [32,512,512]
        else if (in_sizes[0] == 16777216) hb = 1;   // bf16
    }

    hipMemsetAsync(hs, 0, HSB + FLB + 64, stream);  // h=0, flags=0, dtype=0
    if (hb == 1)       hipMemsetAsync(flag, 1, 4, stream);   // nonzero -> bf16
    else if (hb == -1) detect_dtype<<<1, 256, 0, stream>>>((const unsigned int*)d_in[0], flag);

    // Pre-split masked X into d_out scratch (dead until L1 phase writes output).
    prep<<<4096, 256, 0, stream>>>(flag, d_in[0], d_in[1], (char*)d_out);

    // Layer 0: persistent, 512 steps, flag handshake, pipelined x-part.
    lstm_phase<0><<<128, 512, 0, stream>>>(flag, (const char*)d_out, ws,
        hs, flags, d_in[4], d_in[5], d_in[6], d_in[3], d_in[2], d_out,
        os4, write_hn);

    hipMemsetAsync(hs, 0, HSB + FLB, stream);       // reset h + flags, keep dtype

    // Layer 1: persistent; reads OS, writes d_out.
    lstm_phase<1><<<128, 512, 0, stream>>>(flag, (const char*)ws, ws,
        hs, flags, d_in[7], d_in[8], d_in[9], d_in[3], nullptr, d_out,
        os4, write_hn);
}

// Round 5
// 8586.365 us; speedup vs baseline: 1.0867x; 1.0867x over previous
//
#include <hip/hip_runtime.h>
#include <math.h>

typedef unsigned short ushort_t;
typedef short short8 __attribute__((ext_vector_type(8)));
typedef float floatx4 __attribute__((ext_vector_type(4)));
typedef float float4v __attribute__((ext_vector_type(4)));
typedef unsigned int uint4v __attribute__((ext_vector_type(4)));

__device__ __forceinline__ float b2f(ushort_t u) {
    union { unsigned int i; float f; } v; v.i = ((unsigned int)u) << 16; return v.f;
}
__device__ __forceinline__ ushort_t f2b(float f) {
    union { float f; unsigned int i; } v; v.f = f;
    unsigned int x = v.i;
    return (ushort_t)((x + 0x7fffu + ((x >> 16) & 1u)) >> 16);  // RNE
}
__device__ __forceinline__ void split8(const float* v, short8& hi, short8& lo) {
#pragma unroll
    for (int e = 0; e < 8; ++e) {
        ushort_t h = f2b(v[e]);
        hi[e] = (short)h;
        lo[e] = (short)f2b(v[e] - b2f(h));
    }
}
__device__ __forceinline__ void load8f(const float* p, float* v) {
    *(float4v*)(v)     = *(const float4v*)(p);
    *(float4v*)(v + 4) = *(const float4v*)(p + 4);
}
__device__ __forceinline__ floatx4 mfma16(short8 a, short8 b, floatx4 c) {
    return __builtin_amdgcn_mfma_f32_16x16x32_bf16(a, b, c, 0, 0, 0);
}
// Coherent (LLC) stores: bypass L1/L2 so remote XCDs can read them.
__device__ __forceinline__ void store8_cc(void* p, unsigned long long v) {
    asm volatile("global_store_dwordx2 %0, %1, off sc0 sc1"
                 :: "v"(p), "v"(v) : "memory");
}
__device__ __forceinline__ void store4_cc(void* p, unsigned int v) {
    asm volatile("global_store_dword %0, %1, off sc0 sc1"
                 :: "v"(p), "v"(v) : "memory");
}

// Classify input encoding (fallback when in_sizes doesn't resolve it).
__global__ void detect_dtype(const unsigned int* __restrict__ x, int* __restrict__ flag) {
    __shared__ int cnt;
    if (threadIdx.x == 0) cnt = 0;
    __syncthreads();
    int c = 0;
#pragma unroll
    for (int i = 0; i < 8; ++i) {
        unsigned int w = x[threadIdx.x * 8 + i];
        unsigned int e = (w >> 7) & 0xFFu;
        if (e >= 100u && e <= 140u) ++c;
    }
    atomicAdd(&cnt, c);
    __syncthreads();
    if (threadIdx.x == 0) *flag = (cnt > 1024) ? 1 : 0;   // 1 = bf16, 0 = f32
}

// One-time pre-split of masked X into XS (d_out scratch).
__global__ __launch_bounds__(256) void prep(
    const int* __restrict__ flag,
    const void* __restrict__ x, const void* __restrict__ mask_x,
    char* __restrict__ xs)
{
    const bool isbf = (*flag != 0);
    const int i = blockIdx.x * 256 + threadIdx.x;       // 1048576 total
    const int b = i >> 15;
    const int rem = i & 32767;
    const int t = rem >> 6;
    const int c = rem & 63;
    const size_t xoff = ((size_t)(b * 512 + t)) * 512 + c * 8;
    if (isbf) {
        const ushort_t* X = (const ushort_t*)x;
        const ushort_t* M = (const ushort_t*)mask_x + b * 512 + c * 8;
        short8 o;
#pragma unroll
        for (int e = 0; e < 8; ++e) o[e] = (short)f2b(b2f(X[xoff + e]) * b2f(M[e]));
        *(short8*)(xs + ((size_t)t * 32 + b) * 1024 + c * 16) = o;
    } else {
        float v[8], m[8];
        load8f((const float*)x + xoff, v);
        load8f((const float*)mask_x + b * 512 + c * 8, m);
#pragma unroll
        for (int e = 0; e < 8; ++e) v[e] *= m[e];
        short8 hi, lo; split8(v, hi, lo);
        char* p = xs + ((size_t)t * 32 + b) * 2048 + c * 32;
        *(short8*)p = hi; *(short8*)(p + 16) = lo;
    }
}

// LDS swizzle: spreads rows and 64B-segments across banks. Pure fn of (row,o).
__device__ __forceinline__ int lds_swz(int row, int o) {
    return o ^ ((row & 7) << 4) ^ (((o >> 6) & 7) << 4);
}

// Persistent LSTM layer. 128 blocks x 512 thr. Block = (dir, j-tile, m-half);
// wave = (gate q, K-half kh). Weights register/L2-resident.
// Per step: single-wave poll of per-block flags; h staged LLC->LDS; wave 7
// epilogue (preloaded constants) with h-store -> drain -> flag -> bulk stores;
// x-part(s+1) pipelined behind the epilogue by waves 0-6.
template <int LAYER>
__global__ __launch_bounds__(512, 2) void lstm_phase(
    const int* __restrict__ flag,
    const char* __restrict__ xs,     // L0: XS (d_out scratch); L1: OS (ws)
    char* __restrict__ os,           // L0 writes OS here
    char* __restrict__ hs,           // h bufs: [par][dir]*64KB: hi[32][512]2B, lo +32768
    char* __restrict__ flags,        // 128 flag words, 64B apart: [(dir*2+m)*32+jt]
    const void* __restrict__ w_ih, const void* __restrict__ w_hh,
    const void* __restrict__ bias, const void* __restrict__ mask_h,
    const void* __restrict__ mask_out, void* __restrict__ dout,
    int os4_host, int write_hn)
{
    __shared__ __align__(16) char smem[40960];   // h tile 32KB + gbuf 8KB
    float* gb = (float*)(smem + 32768);
    const int dir  = blockIdx.x >> 6;
    const int b6   = blockIdx.x & 63;
    const int jt   = b6 & 31;
    const int m    = b6 >> 5;
    const int j0   = jt << 4;
    const int tid  = threadIdx.x;
    const int w    = tid >> 6;
    const int q    = w & 3;          // gate
    const int kh   = w >> 2;         // K-half
    const int lane = tid & 63;
    const int n16  = lane & 15;
    const int quad = lane >> 4;
    const bool isbf = (*flag != 0);
    const bool os4  = (!isbf) && (os4_host != 0);
    constexpr int KI = (LAYER == 0) ? 512 : 1024;   // ih K total
    constexpr int NIT = (KI / 2) / 32;              // ih 32-K tiles per half: 8 / 16
    constexpr int NH = 8;                           // hh 32-K tiles per half
    const int gq = q * 512 + j0 + n16;              // gate row

    // ---- one-time: weights -> registers (hi/lo) ----
    short8 wih_h[NIT], wih_l[NIT], whh_h[NH], whh_l[NH];
    if (isbf) {
        const ushort_t* WI = (const ushort_t*)w_ih + ((size_t)(dir * 2048 + gq)) * KI + kh * (KI / 2) + quad * 8;
        const ushort_t* WH = (const ushort_t*)w_hh + ((size_t)(dir * 2048 + gq)) * 512 + kh * 256 + quad * 8;
#pragma unroll
        for (int ki = 0; ki < NIT; ++ki) { wih_h[ki] = *(const short8*)(WI + ki * 32); wih_l[ki] = short8{0,0,0,0,0,0,0,0}; }
#pragma unroll
        for (int ki = 0; ki < NH; ++ki) { whh_h[ki] = *(const short8*)(WH + ki * 32); whh_l[ki] = short8{0,0,0,0,0,0,0,0}; }
    } else {
        const float* WI = (const float*)w_ih + ((size_t)(dir * 2048 + gq)) * KI + kh * (KI / 2) + quad * 8;
        const float* WH = (const float*)w_hh + ((size_t)(dir * 2048 + gq)) * 512 + kh * 256 + quad * 8;
#pragma unroll
        for (int ki = 0; ki < NIT; ++ki) { float w8[8]; load8f(WI + ki * 32, w8); split8(w8, wih_h[ki], wih_l[ki]); }
#pragma unroll
        for (int ki = 0; ki < NH; ++ki) { float w8[8]; load8f(WH + ki * 32, w8); split8(w8, whh_h[ki], whh_l[ki]); }
    }

    // x-part of gates for timestep ts (no h dependence)
    auto xpart = [&](int ts) -> floatx4 {
        floatx4 a = {0.f, 0.f, 0.f, 0.f};
        if (isbf) {
            const int stride = (LAYER == 0) ? 1024 : 2048;
            const char* xb = xs + ((size_t)ts * 32 + m * 16 + n16) * stride + (kh * NIT * 4 + quad) * 16;
#pragma unroll
            for (int ki = 0; ki < NIT; ++ki)
                a = mfma16(*(const short8*)(xb + ki * 64), wih_h[ki], a);
        } else if (LAYER == 1 && !os4) {   // compact OS: a_lo==0 exactly
            const char* xb = xs + ((size_t)ts * 32 + m * 16 + n16) * 2048 + (kh * 64 + quad) * 16;
#pragma unroll
            for (int ki = 0; ki < NIT; ++ki) {
                short8 av = *(const short8*)(xb + ki * 64);
                a = mfma16(av, wih_h[ki], a);
                a = mfma16(av, wih_l[ki], a);
            }
        } else {
            const int stride = (LAYER == 0) ? 2048 : 4096;
            const char* xb = xs + ((size_t)ts * 32 + m * 16 + n16) * stride + (kh * NIT * 4 + quad) * 32;
#pragma unroll
            for (int ki = 0; ki < NIT; ++ki) {
                short8 ah = *(const short8*)(xb + ki * 128);
                short8 al = *(const short8*)(xb + ki * 128 + 16);
                a = mfma16(ah, wih_h[ki], a);
                a = mfma16(al, wih_h[ki], a);
                a = mfma16(ah, wih_l[ki], a);
            }
        }
        return a;
    };

    // ---- one-time: epilogue constants (wave-7 lane mapping) -> registers ----
    const int el4 = (lane & 3) * 4;          // first of 4 consecutive j
    const int erow = m * 16 + (lane >> 2);   // batch row
    const int ej0 = j0 + el4;
    float bi4[4] = {0,0,0,0}, bf4[4] = {0,0,0,0}, bg4[4] = {0,0,0,0}, bo4[4] = {0,0,0,0};
    float mh4[4] = {0,0,0,0}, mo4[4] = {0,0,0,0};
    if (w == 7) {
        if (isbf) {
            const ushort_t* BI = (const ushort_t*)bias;
            const ushort_t* MH = (const ushort_t*)mask_h + LAYER * 16384;
#pragma unroll
            for (int u = 0; u < 4; ++u) {
                const int ej = ej0 + u;
                bi4[u] = b2f(BI[dir * 2048 + ej]);        bf4[u] = b2f(BI[dir * 2048 + 512 + ej]);
                bg4[u] = b2f(BI[dir * 2048 + 1024 + ej]); bo4[u] = b2f(BI[dir * 2048 + 1536 + ej]);
                mh4[u] = b2f(MH[erow * 512 + ej]);
                mo4[u] = (LAYER == 0) ? b2f(((const ushort_t*)mask_out)[erow * 1024 + dir * 512 + ej]) : 0.f;
            }
        } else {
            const float* BI = (const float*)bias;
            const float* MH = (const float*)mask_h + LAYER * 16384;
            *(float4v*)bi4 = *(const float4v*)(BI + dir * 2048 + ej0);
            *(float4v*)bf4 = *(const float4v*)(BI + dir * 2048 + 512 + ej0);
            *(float4v*)bg4 = *(const float4v*)(BI + dir * 2048 + 1024 + ej0);
            *(float4v*)bo4 = *(const float4v*)(BI + dir * 2048 + 1536 + ej0);
            *(float4v*)mh4 = *(const float4v*)(MH + erow * 512 + ej0);
            if (LAYER == 0) *(float4v*)mo4 = *(const float4v*)((const float*)mask_out + erow * 1024 + dir * 512 + ej0);
        }
    }
    float creg[4] = {0.f, 0.f, 0.f, 0.f};

    const char* myflags = flags + (size_t)((dir * 2 + m) * 32) * 64;
    floatx4 acc = xpart(dir ? 511 : 0);

    for (int s = 0; s < 512; ++s) {
        const int t = dir ? (511 - s) : s;

        // ============ single-wave poll: all 32 producer flags >= s ==========
        if (w == 0) {
            const char* fb = myflags + (size_t)(lane & 31) * 64;
            int fv;
            for (;;) {
                asm volatile("global_load_dword %0, %1, off sc0 sc1\n\ts_waitcnt vmcnt(0)"
                             : "=v"(fv) : "v"(fb) : "memory");
                if (__all(fv >= s)) break;
            }
        }
        __syncthreads();                                   // barrier A
        __builtin_amdgcn_sched_barrier(0);

        // ============ stage h rows [m*16, m*16+16) LLC -> LDS ==============
        {
            const char* hr = hs + (size_t)((s & 1) * 2 + dir) * 65536;
            const int planes = isbf ? 1 : 2;
            if (tid < planes * 256) {
                const int p = tid >> 8, v = tid & 255;
                const int row = v >> 4, seg = v & 15;
                const char* gsrc = hr + p * 32768 + (size_t)(m * 16 + row) * 1024 + seg * 64;
                uint4v t0, t1, t2, t3;
                asm volatile("global_load_dwordx4 %0, %1, off sc0 sc1" : "=v"(t0) : "v"(gsrc));
                asm volatile("global_load_dwordx4 %0, %1, off sc0 sc1" : "=v"(t1) : "v"(gsrc + 16));
                asm volatile("global_load_dwordx4 %0, %1, off sc0 sc1" : "=v"(t2) : "v"(gsrc + 32));
                asm volatile("global_load_dwordx4 %0, %1, off sc0 sc1" : "=v"(t3) : "v"(gsrc + 48));
                asm volatile("s_waitcnt vmcnt(0)" ::: "memory");
                __builtin_amdgcn_sched_barrier(0);
                char* lbase = smem + p * 16384 + row * 1024;
                *(uint4v*)(lbase + lds_swz(row, seg * 64))      = t0;
                *(uint4v*)(lbase + lds_swz(row, seg * 64 + 16)) = t1;
                *(uint4v*)(lbase + lds_swz(row, seg * 64 + 32)) = t2;
                *(uint4v*)(lbase + lds_swz(row, seg * 64 + 48)) = t3;
            }
        }
        __syncthreads();                                   // barrier B

        // ============ h-part (register W_hh, LDS A-frags) ==================
        {
            const char* hrow = smem + n16 * 1024;
            if (isbf) {
#pragma unroll
                for (int ki = 0; ki < NH; ++ki) {
                    const int o = kh * 512 + ki * 64 + quad * 16;
                    acc = mfma16(*(const short8*)(hrow + lds_swz(n16, o)), whh_h[ki], acc);
                }
            } else {
#pragma unroll
                for (int ki = 0; ki < NH; ++ki) {
                    const int o = kh * 512 + ki * 64 + quad * 16;
                    const int so = lds_swz(n16, o);
                    short8 ah = *(const short8*)(hrow + so);
                    short8 al = *(const short8*)(hrow + 16384 + so);
                    acc = mfma16(ah, whh_h[ki], acc);
                    acc = mfma16(al, whh_h[ki], acc);
                    acc = mfma16(ah, whh_l[ki], acc);
                }
            }
        }

        // ============ K-half gate exchange =================================
#pragma unroll
        for (int r = 0; r < 4; ++r)
            gb[((q * 2 + kh) * 16 + quad * 4 + r) * 16 + n16] = acc[r];
        __syncthreads();                                   // barrier C

        // ============ epilogue: wave 7 only (4 cells/lane) =================
        if (w == 7) {
            float4v gA[8];
#pragma unroll
            for (int z = 0; z < 8; ++z)
                gA[z] = *(const float4v*)(gb + z * 256 + lane * 4);

            float hv4[4], cn4[4];
            unsigned long long hiw = 0ull, low = 0ull;
#pragma unroll
            for (int u = 0; u < 4; ++u) {
                float ig = gA[0][u] + gA[1][u] + bi4[u];
                float fg = gA[2][u] + gA[3][u] + bf4[u];
                float gg = gA[4][u] + gA[5][u] + bg4[u];
                float og = gA[6][u] + gA[7][u] + bo4[u];
                float si = 1.f / (1.f + expf(-ig));
                float sf = 1.f / (1.f + expf(-fg));
                float so = 1.f / (1.f + expf(-og));
                float cn = sf * creg[u] + si * tanhf(gg);
                float h  = so * tanhf(cn);
                creg[u] = cn; hv4[u] = h; cn4[u] = cn;
                float hm = h * mh4[u];
                ushort_t hhi = f2b(hm);
                hiw |= (unsigned long long)hhi << (16 * u);
                low |= (unsigned long long)f2b(hm - b2f(hhi)) << (16 * u);
            }
            // h stores first; drain them; post the flag; THEN bulk stores.
            char* hw = hs + (size_t)(((s + 1) & 1) * 2 + dir) * 65536 + (size_t)erow * 1024 + ej0 * 2;
            store8_cc(hw, hiw);
            if (!isbf) store8_cc(hw + 32768, low);
            asm volatile("s_waitcnt vmcnt(0)" ::: "memory");
            if (lane == 0 && s != 511)
                store4_cc((void*)(myflags + (size_t)jt * 64), (unsigned int)(s + 1));

            const int jg0 = dir * 512 + ej0;
            if constexpr (LAYER == 0) {
                unsigned long long ohi = 0ull, olo = 0ull;
#pragma unroll
                for (int u = 0; u < 4; ++u) {
                    float ho = hv4[u] * mo4[u];
                    ushort_t oh = f2b(ho);
                    ohi |= (unsigned long long)oh << (16 * u);
                    olo |= (unsigned long long)f2b(ho - b2f(oh)) << (16 * u);
                }
                if (os4) {
                    char* op = os + ((size_t)t * 32 + erow) * 4096 + (jg0 >> 3) * 32 + (jg0 & 7) * 2;
                    *(unsigned long long*)op = ohi;
                    *(unsigned long long*)(op + 16) = olo;
                } else {
                    *(unsigned long long*)(os + ((size_t)t * 32 + erow) * 2048 + (size_t)jg0 * 2) = ohi;
                }
            } else {
                size_t o1 = ((size_t)erow * 512 + t) * 1024 + jg0;
                if (isbf) {
                    unsigned long long ow = 0ull;
#pragma unroll
                    for (int u = 0; u < 4; ++u) ow |= (unsigned long long)f2b(hv4[u]) << (16 * u);
                    *(unsigned long long*)((ushort_t*)dout + o1) = ow;
                } else {
                    *(float4v*)((float*)dout + o1) = float4v{hv4[0], hv4[1], hv4[2], hv4[3]};
                }
            }
            if (s == 511 && write_hn) {
                size_t hnidx = 16777216u + (size_t)((LAYER * 2 + dir) * 32 + erow) * 512 + ej0;
                if (isbf) {
                    unsigned long long hw_ = 0ull, cw_ = 0ull;
#pragma unroll
                    for (int u = 0; u < 4; ++u) {
                        hw_ |= (unsigned long long)f2b(hv4[u]) << (16 * u);
                        cw_ |= (unsigned long long)f2b(cn4[u]) << (16 * u);
                    }
                    *(unsigned long long*)((ushort_t*)dout + hnidx) = hw_;
                    *(unsigned long long*)((ushort_t*)dout + hnidx + 65536) = cw_;
                } else {
                    *(float4v*)((float*)dout + hnidx) = float4v{hv4[0], hv4[1], hv4[2], hv4[3]};
                    *(float4v*)((float*)dout + hnidx + 65536) = float4v{cn4[0], cn4[1], cn4[2], cn4[3]};
                }
            }
        }

        // ============ pipelined x-part for step s+1 ========================
        if (s != 511) acc = xpart(dir ? (510 - s) : (s + 1));
    }
}

extern "C" void kernel_launch(void* const* d_in, const int* in_sizes, int n_in,
                              void* d_out, int out_size, void* d_ws, size_t ws_size,
                              hipStream_t stream) {
    char* ws = (char*)d_ws;
    const size_t HSB = 262144;   // h buffers: [2 par][2 dir] * 64KB
    const size_t FLB = 8192;     // 128 flag words, 64B apart
    // ws layout: [OS (67.1MB full | 33.5MB compact)][HS][flags][dtype flag]
    int os4 = (ws_size >= 67108864ull + HSB + FLB + 64) ? 1 : 0;
    size_t osb = os4 ? 67108864ull : 33554432ull;
    char* hs = ws + osb;
    char* flags = hs + HSB;
    int* flag = (int*)(flags + FLB);
    int write_hn = (out_size >= 16908288) ? 1 : 0;

    // dtype from input byte size when unambiguous; sniff otherwise.
    int hb = -1;
    if (in_sizes && n_in > 0) {
        if (in_sizes[0] == 33554432) hb = 0;        // f32 x [32,512,512]
        else if (in_sizes[0] == 16777216) hb = 1;   // bf16
    }

    hipMemsetAsync(hs, 0, HSB + FLB + 64, stream);  // h=0, flags=0, dtype=0
    if (hb == 1)       hipMemsetAsync(flag, 1, 4, stream);   // nonzero -> bf16
    else if (hb == -1) detect_dtype<<<1, 256, 0, stream>>>((const unsigned int*)d_in[0], flag);

    // Pre-split masked X into d_out scratch (dead until L1 phase writes output).
    prep<<<4096, 256, 0, stream>>>(flag, d_in[0], d_in[1], (char*)d_out);

    // Layer 0: persistent, 512 steps, flag handshake, pipelined x-part.
    lstm_phase<0><<<128, 512, 0, stream>>>(flag, (const char*)d_out, ws,
        hs, flags, d_in[4], d_in[5], d_in[6], d_in[3], d_in[2], d_out,
        os4, write_hn);

    hipMemsetAsync(hs, 0, HSB + FLB, stream);       // reset h + flags, keep dtype

    // Layer 1: persistent; reads OS, writes d_out.
    lstm_phase<1><<<128, 512, 0, stream>>>(flag, (const char*)ws, ws,
        hs, flags, d_in[7], d_in[8], d_in[9], d_in[3], nullptr, d_out,
        os4, write_hn);
}